// Round 10
// baseline (144.441 us; speedup 1.0000x reference)
//
#include <hip/hip_runtime.h>
#include <stdint.h>
#include <stddef.h>

typedef _Float16 h2 __attribute__((ext_vector_type(2)));
typedef _Float16 h8 __attribute__((ext_vector_type(8)));
typedef float f4 __attribute__((ext_vector_type(4)));

union Hfrag { h2 p[4]; h8 v; };

// ---------------- workspace layout (bytes) ----------------
// pmin/pmax (K1 partials) are dead after K2; Bt (built in K3) overlays them.
// Bt layout (ring-stage form): 80 sections of 12,288 B.
//   section(ic,half,j) = (ic*2+half)*5 + j ; inside: [o 0..127][80 B row] +
//   2048 B pad (so one section = 3 rounds x 256 thr x 16 B -> stage is
//   exactly 3 uniform gload_lds per thread).  j=0..3 spline cols, j=4 base.
//   Total 983,040 B.
#define WS_PMIN   0               // f32 [512][256] = 512 KB
#define WS_PMAX   524288          // f32 [512][256] = 512 KB
#define WS_BT     0               // 983,040 B (overlays pmin+pmax)
#define WS_SMALL  1048576
#define WS_SCALEV (WS_SMALL + 0)      // f32 [256]
#define WS_BKN    (WS_SMALL + 1024)   // f16 [4][256] knot offsets b_j
#define WS_C0     (WS_SMALL + 3072)   // f32 [256] folded constant column
#define WS_BSC    (WS_SMALL + 4096)
#define WS_BSH    (WS_SMALL + 5120)
#define WS_SSC    (WS_SMALL + 6144)
#define WS_SSH    (WS_SMALL + 7168)

__device__ __forceinline__ void gload_lds16(const void* g, void* l) {
  __builtin_amdgcn_global_load_lds(
      (const __attribute__((address_space(1))) void*)g,
      (__attribute__((address_space(3))) void*)l, 16, 0, 0);
}

// ---------------- K1: per-feature min/max partials ----------------
__global__ __launch_bounds__(256) void kan_minmax(const float* __restrict__ x,
                                                  float* __restrict__ pmin,
                                                  float* __restrict__ pmax) {
  __shared__ f4 smn[4][64], smx[4][64];
  const int b = blockIdx.x, t = threadIdx.x;
  const int fq = t & 63, rg = t >> 6;
  const float* p = x + (size_t)b * 64 * 256 + (size_t)rg * 16 * 256 + fq * 4;
  f4 mn = (f4)(3.402823466e38f), mx = (f4)(-3.402823466e38f);
#pragma unroll
  for (int j = 0; j < 16; ++j) {
    f4 v = *(const f4*)(p + (size_t)j * 256);
    mn = __builtin_elementwise_min(mn, v);
    mx = __builtin_elementwise_max(mx, v);
  }
  smn[rg][fq] = mn; smx[rg][fq] = mx;
  __syncthreads();
  if (rg == 0) {
#pragma unroll
    for (int g = 1; g < 4; ++g) {
      mn = __builtin_elementwise_min(mn, smn[g][fq]);
      mx = __builtin_elementwise_max(mx, smx[g][fq]);
    }
    *(f4*)(pmin + (size_t)b * 256 + fq * 4) = mn;
    *(f4*)(pmax + (size_t)b * 256 + fq * 4) = mx;
  }
}

// ---------------- K2: finalize minmax -> scalev, knot offsets, BN consts ----
__global__ __launch_bounds__(256) void kan_finalize(
    const float* __restrict__ pmin, const float* __restrict__ pmax,
    const float* __restrict__ g1, const float* __restrict__ b1,
    const float* __restrict__ m1, const float* __restrict__ v1,
    const float* __restrict__ g2, const float* __restrict__ b2,
    const float* __restrict__ m2, const float* __restrict__ v2,
    float* __restrict__ scalev, _Float16* __restrict__ bkn,
    float* __restrict__ bscv, float* __restrict__ bshv,
    float* __restrict__ sscv, float* __restrict__ sshv) {
  __shared__ f4 smn[256], smx[256];
  const int t = threadIdx.x, q = blockIdx.x;
  const float* pm = pmin + (size_t)t * 256 + q * 4;
  const float* px = pmax + (size_t)t * 256 + q * 4;
  f4 mn = __builtin_elementwise_min(*(const f4*)pm, *(const f4*)(pm + 256 * 256));
  f4 mx = __builtin_elementwise_max(*(const f4*)px, *(const f4*)(px + 256 * 256));
  smn[t] = mn; smx[t] = mx;
  __syncthreads();
  for (int st = 128; st > 0; st >>= 1) {
    if (t < st) {
      smn[t] = __builtin_elementwise_min(smn[t], smn[t + st]);
      smx[t] = __builtin_elementwise_max(smx[t], smx[t + st]);
    }
    __syncthreads();
  }
  if (t == 0) {
    const f4 fmn = smn[0], fmx = smx[0];
#pragma unroll
    for (int j = 0; j < 4; ++j) {
      const int o = q * 4 + j;
      const float mnS = fmn[j], mxS = fmx[j];
      const float rng = mxS - mnS + 1e-7f;
      scalev[o] = 1.0f / rng;
      const float step = 0.25f * rng;
#pragma unroll
      for (int jj = 0; jj < 4; ++jj)
        bkn[jj * 256 + o] = (_Float16)(mnS + step * (float)jj);
      const float bs = g1[o] / sqrtf(v1[o] + 1e-3f);
      bscv[o] = bs;
      bshv[o] = b1[o] - m1[o] * bs;
      const float ss = g2[o] / sqrtf(v2[o] + 1e-3f);
      sscv[o] = ss;
      sshv[o] = b2[o] - m2[o] * ss;
    }
  }
}

// ---------------- K3: build reduced f16 weight matrix Bt + C0 ----------------
// section = (ic*2+half)*5 + j ; f16 idx = section*6144 + o*40 + kk.
__global__ __launch_bounds__(256) void kan_buildw(
    const float* __restrict__ spline_w, const float* __restrict__ spline_s,
    const float* __restrict__ base_w, const float* __restrict__ scalev,
    _Float16* __restrict__ Bt, float* __restrict__ C0) {
  const int og = blockIdx.x;   // 256 blocks: one output feature each
  const int i  = threadIdx.x;  // input feature
  const float* wp = spline_w + (size_t)(og * 256 + i) * 9;
  const float w1 = wp[1], w2 = wp[2], w3 = wp[3], w4 = wp[4];
  const float w5 = wp[5], w6 = wp[6], w7 = wp[7], w8 = wp[8];
  const float s  = spline_s[og * 256 + i];
  const float sc = scalev[i];
  const float wp0 = 0.25f*w1 + 0.5f*w2 + 0.75f*w3 + w4 + 0.75f*w5 + 0.5f*w6 + 0.25f*w7;
  float wj[4];
  wj[0] = (w5 + w6 + w7 + w8) - (w1 + w2 + w3 + w4);  // xn column
  wj[1] = w1 - 2.0f * w5;                             // relu(xn-1/4)
  wj[2] = w2 - 2.0f * w6;                             // relu(xn-1/2)
  wj[3] = w3 - 2.0f * w7;                             // relu(xn-3/4)
  const float ssc = s * sc;
  const int half = og >> 7, o = og & 127, ic = i >> 5, kk = i & 31;
  const size_t sec0 = (size_t)(ic * 2 + half) * 5;
  const size_t off = (size_t)o * 40 + kk;
#pragma unroll
  for (int j = 0; j < 4; ++j)
    Bt[(sec0 + j) * 6144 + off] = (_Float16)(wj[j] * ssc);
  Bt[(sec0 + 4) * 6144 + off] = (_Float16)base_w[(size_t)i * 256 + og];
  __shared__ float red[256];
  red[i] = wp0 * s;
  __syncthreads();
  for (int st = 128; st > 0; st >>= 1) {
    if (i < st) red[i] += red[i + st];
    __syncthreads();
  }
  if (i == 0) C0[og] = red[0];
}

// ---------------- K4: fused dual GEMM + BN + SiLU (ring-slot pipeline) ------
// 128x128 tile, 4 waves 2x2, per-wave 64x64, 512 blocks = 2 blocks/CU
// (independent-block stall decorrelation, the r7 property).  m201-style
// per-SUBSTEP schedule: ring of 6 x 12KB j-group slots; at substep (ic,j)
// stage (ic+1,j) -- 5 substeps of flight -- with counted vmcnt {12,20,20,20,-}
// (never 0 in the loop), raw s_barrier per substep, b0/b1 static ping-pong,
// setprio(1) around each 16-MFMA cluster (T5: now phase-split).
__global__ __launch_bounds__(256, 2) void kan_gemm(
    const float* __restrict__ x, const _Float16* __restrict__ Bt,
    const _Float16* __restrict__ bkn, const float* __restrict__ C0,
    const float* __restrict__ bscv, const float* __restrict__ bshv,
    const float* __restrict__ sscv, const float* __restrict__ sshv,
    float* __restrict__ out) {
  const int tid = threadIdx.x;
  const int lane = tid & 63;
  const int wv = tid >> 6;
  const int wm = wv >> 1, wn = wv & 1;
  const int lr = lane & 15, lg = lane >> 4;
  const int mt = blockIdx.x & 255, nt = blockIdx.x >> 8;

  const int rowA = mt * 128 + wm * 64 + lr;
  const int colB = wn * 64 + lr;

  __shared__ __align__(16) char smem[75776];   // 6 x 12288 slots + 2048 sbkn
  _Float16* sbkn = (_Float16*)(smem + 73728);
  *(uint2*)((char*)sbkn + tid * 8) = ((const uint2*)bkn)[tid];

  f4 accS[4][4], accB[4][4];
#pragma unroll
  for (int m = 0; m < 4; ++m)
#pragma unroll
    for (int n = 0; n < 4; ++n) { accS[m][n] = (f4)0.0f; accB[m][n] = (f4)0.0f; }

  h2 hz; hz[0] = (_Float16)0.0f; hz[1] = (_Float16)0.0f;

  const int rowb = colB * 80 + lg * 16;        // per-lane row base within slot

// stage section (ICP, J) of this block's nt-half into ring slot SLOT:
// exactly 3 gload_lds per thread (uniform -> counted vmcnt sound cross-wave)
#define STAGE(ICP, J, SLOT)                                                  \
  {                                                                          \
    const char* gs = (const char*)Bt + (size_t)((((ICP) * 2 + nt) * 5) + (J)) * 12288; \
    _Pragma("unroll")                                                        \
    for (int r = 0; r < 3; ++r)                                              \
      gload_lds16(gs + (size_t)(r * 256 + tid) * 16,                         \
                  smem + (SLOT) * 12288 + r * 4096 + wv * 1024);             \
  }

#define LOADB(BF, SLOT)                                                      \
  _Pragma("unroll")                                                          \
  for (int n = 0; n < 4; ++n)                                                \
    BF[n].v = *(const h8*)(smem + (SLOT) * 12288 + rowb + n * 1280);

#define SPLINE_STEP(J, BF, IC)                                               \
  {                                                                          \
    Hfrag bbj;                                                               \
    bbj.v = *(const h8*)(sbkn + (J) * 256 + (IC) * 32 + lg * 8);             \
    Hfrag af[4];                                                             \
    _Pragma("unroll")                                                        \
    for (int m = 0; m < 4; ++m)                                              \
      _Pragma("unroll")                                                      \
      for (int qq = 0; qq < 4; ++qq) {                                       \
        h2 d = xh[m].p[qq] - bbj.p[qq];                                      \
        af[m].p[qq] = __builtin_elementwise_max(d, hz);                      \
      }                                                                      \
    __builtin_amdgcn_s_setprio(1);                                           \
    _Pragma("unroll")                                                        \
    for (int m = 0; m < 4; ++m)                                              \
      _Pragma("unroll")                                                      \
      for (int n = 0; n < 4; ++n)                                            \
        accS[m][n] = __builtin_amdgcn_mfma_f32_16x16x32_f16(af[m].v, BF[n].v,\
                                                            accS[m][n], 0, 0, 0); \
    __builtin_amdgcn_s_setprio(0);                                           \
  }

#define BASE_STEP(BF)                                                        \
  {                                                                          \
    __builtin_amdgcn_s_setprio(1);                                           \
    _Pragma("unroll")                                                        \
    for (int m = 0; m < 4; ++m)                                              \
      _Pragma("unroll")                                                      \
      for (int n = 0; n < 4; ++n)                                            \
        accB[m][n] = __builtin_amdgcn_mfma_f32_16x16x32_f16(xh[m].v, BF[n].v,\
                                                            accB[m][n], 0, 0, 0); \
    __builtin_amdgcn_s_setprio(0);                                           \
  }

#define CVT_XH()                                                             \
  _Pragma("unroll")                                                          \
  for (int m = 0; m < 4; ++m) {                                              \
    xh[m].p[0][0] = (_Float16)xa[m].x; xh[m].p[0][1] = (_Float16)xa[m].y;    \
    xh[m].p[1][0] = (_Float16)xa[m].z; xh[m].p[1][1] = (_Float16)xa[m].w;    \
    xh[m].p[2][0] = (_Float16)xb[m].x; xh[m].p[2][1] = (_Float16)xb[m].y;    \
    xh[m].p[3][0] = (_Float16)xb[m].z; xh[m].p[3][1] = (_Float16)xb[m].w;    \
  }

#define LOAD_X(IC)                                                           \
  {                                                                          \
    const int ib = (IC) * 32 + lg * 8;                                       \
    _Pragma("unroll")                                                        \
    for (int m = 0; m < 4; ++m) {                                            \
      const float* px = x + (size_t)(rowA + m * 16) * 256 + ib;              \
      xa[m] = *(const f4*)px; xb[m] = *(const f4*)(px + 4);                  \
    }                                                                        \
  }

  f4 xa[4], xb[4];
  Hfrag xh[4];
  // prologue: X(0) first (FIFO: oldest), then sections (0,0..4) -> slots 0..4
  LOAD_X(0)
#pragma unroll
  for (int j = 0; j < 5; ++j) STAGE(0, j, j)
  asm volatile("s_waitcnt lgkmcnt(0)" ::: "memory");  // sbkn ds_write drained

  int base = 0;                                  // slot of (ic, 0)
#pragma unroll 1
  for (int ic = 0; ic < 7; ++ic) {
    int rs0 = base;
    int rs1 = rs0 + 1; if (rs1 >= 6) rs1 -= 6;
    int rs2 = rs1 + 1; if (rs2 >= 6) rs2 -= 6;
    int rs3 = rs2 + 1; if (rs3 >= 6) rs3 -= 6;
    int rs4 = rs3 + 1; if (rs4 >= 6) rs4 -= 6;
    const int ws0 = rs0 ? rs0 - 1 : 5;           // ws_j = rs_j - 1 (mod 6)

    Hfrag b0[4], b1[4];

    // ---- substep j=0: barrier | stage(ic+1,0) | vmcnt(12) | cvt+X | step0
    __builtin_amdgcn_s_barrier();
    __builtin_amdgcn_sched_barrier(0);
    STAGE(ic + 1, 0, ws0)
    __builtin_amdgcn_sched_barrier(0);
    asm volatile("s_waitcnt vmcnt(12)" ::: "memory");  // drains S(ic,0),X(ic),S(ic,1)
    __builtin_amdgcn_sched_barrier(0);
    LOADB(b0, rs0)
    LOADB(b1, rs1)
    CVT_XH()
    LOAD_X(ic + 1)                               // X(ic+1), newest in FIFO
    SPLINE_STEP(0, b0, ic)

    // ---- substep j=1
    __builtin_amdgcn_s_barrier();
    __builtin_amdgcn_sched_barrier(0);
    STAGE(ic + 1, 1, rs0)
    __builtin_amdgcn_sched_barrier(0);
    asm volatile("s_waitcnt vmcnt(20)" ::: "memory");  // drains S(ic,2)
    __builtin_amdgcn_sched_barrier(0);
    LOADB(b0, rs2)
    SPLINE_STEP(1, b1, ic)

    // ---- substep j=2
    __builtin_amdgcn_s_barrier();
    __builtin_amdgcn_sched_barrier(0);
    STAGE(ic + 1, 2, rs1)
    __builtin_amdgcn_sched_barrier(0);
    asm volatile("s_waitcnt vmcnt(20)" ::: "memory");  // drains S(ic,3)
    __builtin_amdgcn_sched_barrier(0);
    LOADB(b1, rs3)
    SPLINE_STEP(2, b0, ic)

    // ---- substep j=3
    __builtin_amdgcn_s_barrier();
    __builtin_amdgcn_sched_barrier(0);
    STAGE(ic + 1, 3, rs2)
    __builtin_amdgcn_sched_barrier(0);
    asm volatile("s_waitcnt vmcnt(20)" ::: "memory");  // drains S(ic,4)
    __builtin_amdgcn_sched_barrier(0);
    LOADB(b0, rs4)
    SPLINE_STEP(3, b1, ic)

    // ---- substep j=4 (base): barrier | stage(ic+1,4) | no wait | base MFMA
    __builtin_amdgcn_s_barrier();
    __builtin_amdgcn_sched_barrier(0);
    STAGE(ic + 1, 4, rs3)
    __builtin_amdgcn_sched_barrier(0);
    BASE_STEP(b0)

    base = base ? base - 1 : 5;                  // slot(ic+1,0) = base-1 mod 6
  }

  { // ---- tail chunk ic=7: everything staged; single drain, no barriers
    __builtin_amdgcn_s_barrier();
    __builtin_amdgcn_sched_barrier(0);
    asm volatile("s_waitcnt vmcnt(0)" ::: "memory");
    __builtin_amdgcn_sched_barrier(0);
    int rs0 = base;                              // = 5
    int rs1 = rs0 + 1; if (rs1 >= 6) rs1 -= 6;
    int rs2 = rs1 + 1; if (rs2 >= 6) rs2 -= 6;
    int rs3 = rs2 + 1; if (rs3 >= 6) rs3 -= 6;
    int rs4 = rs3 + 1; if (rs4 >= 6) rs4 -= 6;
    Hfrag b0[4], b1[4];
    CVT_XH()
    LOADB(b0, rs0)
    LOADB(b1, rs1)
    SPLINE_STEP(0, b0, 7)
    LOADB(b0, rs2)
    SPLINE_STEP(1, b1, 7)
    LOADB(b1, rs3)
    SPLINE_STEP(2, b0, 7)
    LOADB(b0, rs4)
    SPLINE_STEP(3, b1, 7)
    BASE_STEP(b0)
  }
#undef SPLINE_STEP
#undef BASE_STEP
#undef LOADB
#undef STAGE
#undef CVT_XH
#undef LOAD_X

  // epilogue: out = silu(accB*bs + bsh) + accS*ss + (ssh + ss*C0)
#pragma unroll
  for (int n = 0; n < 4; ++n) {
    const int col = nt * 128 + colB + n * 16;
    const float vbs = bscv[col], vbh = bshv[col];
    const float vss = sscv[col];
    const float vsh = sshv[col] + vss * C0[col];
#pragma unroll
    for (int m = 0; m < 4; ++m) {
      const int row0 = mt * 128 + wm * 64 + m * 16 + lg * 4;
#pragma unroll
      for (int r = 0; r < 4; ++r) {
        const float zb = accB[m][n][r] * vbs + vbh;
        const float si = zb / (1.0f + __expf(-zb));
        const float val = si + accS[m][n][r] * vss + vsh;
        out[(size_t)(row0 + r) * 256 + col] = val;
      }
    }
  }
}

extern "C" void kernel_launch(void* const* d_in, const int* in_sizes, int n_in,
                              void* d_out, int out_size, void* d_ws, size_t ws_size,
                              hipStream_t stream) {
  const float* x        = (const float*)d_in[0];
  const float* base_w   = (const float*)d_in[1];
  const float* spline_w = (const float*)d_in[2];
  const float* spline_s = (const float*)d_in[3];
  const float* g1 = (const float*)d_in[4];
  const float* b1 = (const float*)d_in[5];
  const float* m1 = (const float*)d_in[6];
  const float* v1 = (const float*)d_in[7];
  const float* g2 = (const float*)d_in[8];
  const float* b2 = (const float*)d_in[9];
  const float* m2 = (const float*)d_in[10];
  const float* v2 = (const float*)d_in[11];
  float* out = (float*)d_out;
  char* ws = (char*)d_ws;

  float* pmin     = (float*)(ws + WS_PMIN);
  float* pmax     = (float*)(ws + WS_PMAX);
  _Float16* Bt    = (_Float16*)(ws + WS_BT);
  float* scalev   = (float*)(ws + WS_SCALEV);
  _Float16* bkn   = (_Float16*)(ws + WS_BKN);
  float* C0       = (float*)(ws + WS_C0);
  float* bscv     = (float*)(ws + WS_BSC);
  float* bshv     = (float*)(ws + WS_BSH);
  float* sscv     = (float*)(ws + WS_SSC);
  float* sshv     = (float*)(ws + WS_SSH);

  kan_minmax<<<512, 256, 0, stream>>>(x, pmin, pmax);
  kan_finalize<<<64, 256, 0, stream>>>(pmin, pmax, g1, b1, m1, v1, g2, b2, m2, v2,
                                       scalev, bkn, bscv, bshv, sscv, sshv);
  kan_buildw<<<256, 256, 0, stream>>>(spline_w, spline_s, base_w, scalev, Bt, C0);
  kan_gemm<<<512, 256, 0, stream>>>(x, Bt, bkn, C0, bscv, bshv, sscv, sshv, out);
}

// Round 11
// 143.060 us; speedup vs baseline: 1.0096x; 1.0096x over previous
//
#include <hip/hip_runtime.h>
#include <stdint.h>
#include <stddef.h>

typedef _Float16 h2 __attribute__((ext_vector_type(2)));
typedef _Float16 h8 __attribute__((ext_vector_type(8)));
typedef float f4 __attribute__((ext_vector_type(4)));

union Hfrag { h2 p[4]; h8 v; };

// ---------------- workspace layout (bytes) ----------------
// pmin/pmax (K1 partials) are dead after K2; Bt (built in K3) overlays them.
// Bt layout (bank-conflict-free form): 16 sections of 40,960 B.
//   section(ic,half) = ic*2 + half.  Inside: [j 0..4][slot 0..3][o 0..127][16B]
//   where slot = kk>>3 (k-group) and the 16 B hold kk = slot*8..slot*8+7.
//   A lg-group's ds_read_b128s hit 256 CONTIGUOUS bytes -> banks 0..31 x2
//   (2-way = free).  The 80B-stride layout of r6-r10 only ever touched banks
//   = 0 mod 4 (gcd(20,32)=4) -> measured 1.31M conflicts/dispatch.
//   j=0..3 spline cols, j=4 base.  Section = 2560 lines = 10 loads/thread.
#define WS_PMIN   0               // f32 [512][256] = 512 KB
#define WS_PMAX   524288          // f32 [512][256] = 512 KB
#define WS_BT     0               // 655,360 B (overlays pmin+pmax)
#define WS_SMALL  1048576
#define WS_SCALEV (WS_SMALL + 0)      // f32 [256]
#define WS_BKN    (WS_SMALL + 1024)   // f16 [3][256] db_j = j*0.25*rng, j=1..3
#define WS_MINV   (WS_SMALL + 3072)   // f32 [256] per-feature min
#define WS_C0     (WS_SMALL + 4096)   // f32 [256] spline const column
#define WS_CB     (WS_SMALL + 5120)   // f32 [256] base fold: sum_i mn_i*Wb[i,o]
#define WS_BSC    (WS_SMALL + 6144)
#define WS_BSH    (WS_SMALL + 7168)
#define WS_SSC    (WS_SMALL + 8192)
#define WS_SSH    (WS_SMALL + 9216)

__device__ __forceinline__ void gload_lds16(const void* g, void* l) {
  __builtin_amdgcn_global_load_lds(
      (const __attribute__((address_space(1))) void*)g,
      (__attribute__((address_space(3))) void*)l, 16, 0, 0);
}

// ---------------- K1: per-feature min/max partials ----------------
__global__ __launch_bounds__(256) void kan_minmax(const float* __restrict__ x,
                                                  float* __restrict__ pmin,
                                                  float* __restrict__ pmax) {
  __shared__ f4 smn[4][64], smx[4][64];
  const int b = blockIdx.x, t = threadIdx.x;
  const int fq = t & 63, rg = t >> 6;
  const float* p = x + (size_t)b * 64 * 256 + (size_t)rg * 16 * 256 + fq * 4;
  f4 mn = (f4)(3.402823466e38f), mx = (f4)(-3.402823466e38f);
#pragma unroll
  for (int j = 0; j < 16; ++j) {
    f4 v = *(const f4*)(p + (size_t)j * 256);
    mn = __builtin_elementwise_min(mn, v);
    mx = __builtin_elementwise_max(mx, v);
  }
  smn[rg][fq] = mn; smx[rg][fq] = mx;
  __syncthreads();
  if (rg == 0) {
#pragma unroll
    for (int g = 1; g < 4; ++g) {
      mn = __builtin_elementwise_min(mn, smn[g][fq]);
      mx = __builtin_elementwise_max(mx, smx[g][fq]);
    }
    *(f4*)(pmin + (size_t)b * 256 + fq * 4) = mn;
    *(f4*)(pmax + (size_t)b * 256 + fq * 4) = mx;
  }
}

// ---------------- K2: finalize minmax -> scalev, minv, db offsets, BN consts -
__global__ __launch_bounds__(256) void kan_finalize(
    const float* __restrict__ pmin, const float* __restrict__ pmax,
    const float* __restrict__ g1, const float* __restrict__ b1,
    const float* __restrict__ m1, const float* __restrict__ v1,
    const float* __restrict__ g2, const float* __restrict__ b2,
    const float* __restrict__ m2, const float* __restrict__ v2,
    float* __restrict__ scalev, _Float16* __restrict__ bkn,
    float* __restrict__ minv,
    float* __restrict__ bscv, float* __restrict__ bshv,
    float* __restrict__ sscv, float* __restrict__ sshv) {
  __shared__ f4 smn[256], smx[256];
  const int t = threadIdx.x, q = blockIdx.x;
  const float* pm = pmin + (size_t)t * 256 + q * 4;
  const float* px = pmax + (size_t)t * 256 + q * 4;
  f4 mn = __builtin_elementwise_min(*(const f4*)pm, *(const f4*)(pm + 256 * 256));
  f4 mx = __builtin_elementwise_max(*(const f4*)px, *(const f4*)(px + 256 * 256));
  smn[t] = mn; smx[t] = mx;
  __syncthreads();
  for (int st = 128; st > 0; st >>= 1) {
    if (t < st) {
      smn[t] = __builtin_elementwise_min(smn[t], smn[t + st]);
      smx[t] = __builtin_elementwise_max(smx[t], smx[t + st]);
    }
    __syncthreads();
  }
  if (t == 0) {
    const f4 fmn = smn[0], fmx = smx[0];
#pragma unroll
    for (int j = 0; j < 4; ++j) {
      const int o = q * 4 + j;
      const float mnS = fmn[j], mxS = fmx[j];
      const float rng = mxS - mnS + 1e-7f;
      scalev[o] = 1.0f / rng;
      minv[o] = mnS;
      const float step = 0.25f * rng;
#pragma unroll
      for (int jj = 1; jj < 4; ++jj)
        bkn[(jj - 1) * 256 + o] = (_Float16)(step * (float)jj);
      const float bs = g1[o] / sqrtf(v1[o] + 1e-3f);
      bscv[o] = bs;
      bshv[o] = b1[o] - m1[o] * bs;
      const float ss = g2[o] / sqrtf(v2[o] + 1e-3f);
      sscv[o] = ss;
      sshv[o] = b2[o] - m2[o] * ss;
    }
  }
}

// ---------------- K3: build reduced f16 weight matrix Bt + C0 + Cb ----------
// 8 triangle bases on xn in [0,1) span {1, xn, relu(xn-1/4), relu(xn-1/2),
// relu(xn-3/4)}.  Const column -> C0; scale sc folds into Bt.  j=0 column is
// LINEAR (relu(x-mn) = x-mn >= 0 always), so GEMM A0 = f16(x-mn) serves BOTH
// j=0-spline and base; base corrected by Cb[o] = sum_i mn_i*Wb[i,o].
// Bt f16 idx = (ic*2+half)*20480 + j*4096 + (kk>>3)*1024 + o*8 + (kk&7).
__global__ __launch_bounds__(256) void kan_buildw(
    const float* __restrict__ spline_w, const float* __restrict__ spline_s,
    const float* __restrict__ base_w, const float* __restrict__ scalev,
    const float* __restrict__ minv,
    _Float16* __restrict__ Bt, float* __restrict__ C0, float* __restrict__ Cb) {
  const int og = blockIdx.x;   // 256 blocks: one output feature each
  const int i  = threadIdx.x;  // input feature
  const float* wp = spline_w + (size_t)(og * 256 + i) * 9;
  const float w1 = wp[1], w2 = wp[2], w3 = wp[3], w4 = wp[4];
  const float w5 = wp[5], w6 = wp[6], w7 = wp[7], w8 = wp[8];
  const float s  = spline_s[og * 256 + i];
  const float sc = scalev[i];
  const float bw = base_w[(size_t)i * 256 + og];
  const float wp0 = 0.25f*w1 + 0.5f*w2 + 0.75f*w3 + w4 + 0.75f*w5 + 0.5f*w6 + 0.25f*w7;
  float wj[4];
  wj[0] = (w5 + w6 + w7 + w8) - (w1 + w2 + w3 + w4);  // xn column
  wj[1] = w1 - 2.0f * w5;                             // relu(xn-1/4)
  wj[2] = w2 - 2.0f * w6;                             // relu(xn-1/2)
  wj[3] = w3 - 2.0f * w7;                             // relu(xn-3/4)
  const float ssc = s * sc;
  const int half = og >> 7, o = og & 127, ic = i >> 5, kk = i & 31;
  const size_t base = (size_t)(ic * 2 + half) * 20480 +
                      (size_t)(kk >> 3) * 1024 + (size_t)o * 8 + (kk & 7);
#pragma unroll
  for (int j = 0; j < 4; ++j)
    Bt[base + (size_t)j * 4096] = (_Float16)(wj[j] * ssc);
  Bt[base + 4 * 4096] = (_Float16)bw;
  __shared__ float red[256];
  red[i] = wp0 * s;
  __syncthreads();
  for (int st = 128; st > 0; st >>= 1) {
    if (i < st) red[i] += red[i + st];
    __syncthreads();
  }
  if (i == 0) C0[og] = red[0];
  __syncthreads();
  red[i] = minv[i] * bw;
  __syncthreads();
  for (int st = 128; st > 0; st >>= 1) {
    if (i < st) red[i] += red[i + st];
    __syncthreads();
  }
  if (i == 0) Cb[og] = red[0];
}

// ---------------- K4: fused dual GEMM + BN + SiLU (conflict-free LDS) -------
// r7 skeleton (the best-equal schedule): 128x128 tile, 4 waves 2x2, per-wave
// 64x64, 512 blocks = 2 blocks/CU, single 40KB stage per chunk with one
// vmcnt(0)+barrier.  Changes vs r7: (1) [j][slot][o][16B] LDS layout -> each
// lg-group reads 256 contiguous bytes, bank conflicts 1.31M -> ~0;
// (2) A0 = f16(x - mn) shared by j0-spline AND base (j0 needs no relu: x-mn
// >= 0), spline j=1..3 A = max(A0 - db_j, 0); base fixed up by Cb in epilogue.
__global__ __launch_bounds__(256, 2) void kan_gemm(
    const float* __restrict__ x, const _Float16* __restrict__ Bt,
    const _Float16* __restrict__ bkn, const float* __restrict__ minv,
    const float* __restrict__ C0, const float* __restrict__ Cb,
    const float* __restrict__ bscv, const float* __restrict__ bshv,
    const float* __restrict__ sscv, const float* __restrict__ sshv,
    float* __restrict__ out) {
  const int tid = threadIdx.x;
  const int lane = tid & 63;
  const int wv = tid >> 6;
  const int wm = wv >> 1, wn = wv & 1;
  const int lr = lane & 15, lg = lane >> 4;
  const int mt = blockIdx.x & 255, nt = blockIdx.x >> 8;

  const int rowA = mt * 128 + wm * 64 + lr;
  const int colB = wn * 64 + lr;

  __shared__ __align__(16) char smem[43520];   // 40960 stage + 1024 mn + 1536 db
  float* smnf = (float*)(smem + 40960);
  _Float16* sdb = (_Float16*)(smem + 41984);
  smnf[tid] = minv[tid];
  if (tid < 192) ((uint2*)sdb)[tid] = ((const uint2*)bkn)[tid];

  f4 accS[4][4], accB[4][4];
#pragma unroll
  for (int m = 0; m < 4; ++m)
#pragma unroll
    for (int n = 0; n < 4; ++n) { accS[m][n] = (f4)0.0f; accB[m][n] = (f4)0.0f; }

  h2 hz; hz[0] = (_Float16)0.0f; hz[1] = (_Float16)0.0f;

// stage section (ic, nt): exactly 10 gload_lds per thread, linear
#define STAGE(IC)                                                            \
  {                                                                          \
    const char* gs = (const char*)Bt + (size_t)((IC) * 2 + nt) * 40960;      \
    _Pragma("unroll")                                                        \
    for (int r = 0; r < 10; ++r)                                             \
      gload_lds16(gs + (size_t)(r * 256 + tid) * 16, smem + r * 4096 + wv * 1024); \
  }

// B frags: j-group J, frag n at J*8192 + lg*2048 + colB*16 + n*256 (contig!)
#define LOADB(BF, J)                                                         \
  _Pragma("unroll")                                                          \
  for (int n = 0; n < 4; ++n)                                                \
    BF[n].v = *(const h8*)(smem + (J) * 8192 + lg * 2048 + colB * 16 + n * 256);

// spline sub-step j (j=1..3): A = max(A0 - db_j, 0); db broadcast from LDS
#define SPLINE_STEP(J, BF)                                                   \
  {                                                                          \
    Hfrag bbj;                                                               \
    bbj.v = *(const h8*)(sdb + ((J) - 1) * 256 + ic * 32 + lg * 8);          \
    _Pragma("unroll")                                                        \
    for (int m = 0; m < 4; ++m) {                                            \
      Hfrag afm;                                                             \
      _Pragma("unroll")                                                      \
      for (int qq = 0; qq < 4; ++qq) {                                       \
        h2 d = xh[m].p[qq] - bbj.p[qq];                                      \
        afm.p[qq] = __builtin_elementwise_max(d, hz);                        \
      }                                                                      \
      _Pragma("unroll")                                                      \
      for (int n = 0; n < 4; ++n)                                            \
        accS[m][n] = __builtin_amdgcn_mfma_f32_16x16x32_f16(afm.v, BF[n].v,  \
                                                            accS[m][n], 0, 0, 0); \
    }                                                                        \
  }

  f4 xa[4], xb[4];
  { // prologue: x fragment for ic=0
    const int ib = lg * 8;
#pragma unroll
    for (int m = 0; m < 4; ++m) {
      const float* px = x + (size_t)(rowA + m * 16) * 256 + ib;
      xa[m] = *(const f4*)px; xb[m] = *(const f4*)(px + 4);
    }
  }

#pragma unroll 1
  for (int ic = 0; ic < 8; ++ic) {
    __syncthreads();   // previous chunk's smem reads done (ic=0: aux writes)
    STAGE(ic)
    asm volatile("s_waitcnt vmcnt(0)" ::: "memory");  // stage(ic) + x(ic)
    __syncthreads();

    // A0 = f16(x - mn): f32 subtract (exact min), single rounding
    const f4* smn4 = (const f4*)smnf;
    const f4 mn0 = smn4[ic * 8 + lg * 2], mn1 = smn4[ic * 8 + lg * 2 + 1];
    Hfrag xh[4];
#pragma unroll
    for (int m = 0; m < 4; ++m) {
      f4 na = xa[m] - mn0, nb = xb[m] - mn1;
      xh[m].p[0][0] = (_Float16)na.x; xh[m].p[0][1] = (_Float16)na.y;
      xh[m].p[1][0] = (_Float16)na.z; xh[m].p[1][1] = (_Float16)na.w;
      xh[m].p[2][0] = (_Float16)nb.x; xh[m].p[2][1] = (_Float16)nb.y;
      xh[m].p[3][0] = (_Float16)nb.z; xh[m].p[3][1] = (_Float16)nb.w;
    }

    // x prefetch for ic+1 (drained by next chunk's vmcnt(0))
    __builtin_amdgcn_sched_barrier(0);
    if (ic < 7) {
      const int ib = (ic + 1) * 32 + lg * 8;
#pragma unroll
      for (int m = 0; m < 4; ++m) {
        const float* px = x + (size_t)(rowA + m * 16) * 256 + ib;
        xa[m] = *(const f4*)px; xb[m] = *(const f4*)(px + 4);
      }
    }
    __builtin_amdgcn_sched_barrier(0);

    Hfrag bfA[4], bfB[4];
    LOADB(bfA, 0)
    LOADB(bfB, 1)
    // j=0 spline: A = A0 verbatim (linear column)
#pragma unroll
    for (int m = 0; m < 4; ++m)
#pragma unroll
      for (int n = 0; n < 4; ++n)
        accS[m][n] = __builtin_amdgcn_mfma_f32_16x16x32_f16(xh[m].v, bfA[n].v, accS[m][n], 0, 0, 0);
    LOADB(bfA, 2)
    SPLINE_STEP(1, bfB)
    LOADB(bfB, 3)
    SPLINE_STEP(2, bfA)
    LOADB(bfA, 4)                      // base weights
    SPLINE_STEP(3, bfB)
    // base: A = A0 (corrected by Cb in epilogue)
#pragma unroll
    for (int m = 0; m < 4; ++m)
#pragma unroll
      for (int n = 0; n < 4; ++n)
        accB[m][n] = __builtin_amdgcn_mfma_f32_16x16x32_f16(xh[m].v, bfA[n].v, accB[m][n], 0, 0, 0);
  }
#undef SPLINE_STEP
#undef LOADB
#undef STAGE

  // epilogue: zb = accB*bs + (bsh + bs*Cb); out = silu(zb) + accS*ss + (ssh + ss*C0)
#pragma unroll
  for (int n = 0; n < 4; ++n) {
    const int col = nt * 128 + colB + n * 16;
    const float vbs = bscv[col], vbh = bshv[col] + vbs * Cb[col];
    const float vss = sscv[col];
    const float vsh = sshv[col] + vss * C0[col];
#pragma unroll
    for (int m = 0; m < 4; ++m) {
      const int row0 = mt * 128 + wm * 64 + m * 16 + lg * 4;
#pragma unroll
      for (int r = 0; r < 4; ++r) {
        const float zb = accB[m][n][r] * vbs + vbh;
        const float si = zb / (1.0f + __expf(-zb));
        const float val = si + accS[m][n][r] * vss + vsh;
        out[(size_t)(row0 + r) * 256 + col] = val;
      }
    }
  }
}

extern "C" void kernel_launch(void* const* d_in, const int* in_sizes, int n_in,
                              void* d_out, int out_size, void* d_ws, size_t ws_size,
                              hipStream_t stream) {
  const float* x        = (const float*)d_in[0];
  const float* base_w   = (const float*)d_in[1];
  const float* spline_w = (const float*)d_in[2];
  const float* spline_s = (const float*)d_in[3];
  const float* g1 = (const float*)d_in[4];
  const float* b1 = (const float*)d_in[5];
  const float* m1 = (const float*)d_in[6];
  const float* v1 = (const float*)d_in[7];
  const float* g2 = (const float*)d_in[8];
  const float* b2 = (const float*)d_in[9];
  const float* m2 = (const float*)d_in[10];
  const float* v2 = (const float*)d_in[11];
  float* out = (float*)d_out;
  char* ws = (char*)d_ws;

  float* pmin     = (float*)(ws + WS_PMIN);
  float* pmax     = (float*)(ws + WS_PMAX);
  _Float16* Bt    = (_Float16*)(ws + WS_BT);
  float* scalev   = (float*)(ws + WS_SCALEV);
  _Float16* bkn   = (_Float16*)(ws + WS_BKN);
  float* minv     = (float*)(ws + WS_MINV);
  float* C0       = (float*)(ws + WS_C0);
  float* Cb       = (float*)(ws + WS_CB);
  float* bscv     = (float*)(ws + WS_BSC);
  float* bshv     = (float*)(ws + WS_BSH);
  float* sscv     = (float*)(ws + WS_SSC);
  float* sshv     = (float*)(ws + WS_SSH);

  kan_minmax<<<512, 256, 0, stream>>>(x, pmin, pmax);
  kan_finalize<<<64, 256, 0, stream>>>(pmin, pmax, g1, b1, m1, v1, g2, b2, m2, v2,
                                       scalev, bkn, minv, bscv, bshv, sscv, sshv);
  kan_buildw<<<256, 256, 0, stream>>>(spline_w, spline_s, base_w, scalev, minv,
                                      Bt, C0, Cb);
  kan_gemm<<<512, 256, 0, stream>>>(x, Bt, bkn, minv, C0, Cb,
                                    bscv, bshv, sscv, sshv, out);
}